// Round 1
// baseline (83.462 us; speedup 1.0000x reference)
//
#include <hip/hip_runtime.h>
#include <float.h>
#include <math.h>

#define NB 8192      // batch
#define NC 128       // classes
#define NT 64        // time steps
#define ACE_EPS 1e-5f

// ---------------------------------------------------------------------------
// 1) exclusive prefix sum of target_lengths (B=8192) — single block, 256 thr
// ---------------------------------------------------------------------------
__global__ void prefix_kernel(const int* __restrict__ lens,
                              int* __restrict__ prefix, int n) {
  __shared__ int sums[256];
  const int tid = threadIdx.x;
  const int chunk = n / 256;          // 32
  const int base = tid * chunk;
  int s = 0;
  for (int i = 0; i < chunk; ++i) s += lens[base + i];
  sums[tid] = s;
  __syncthreads();
  // Hillis-Steele inclusive scan over the 256 chunk sums
  for (int off = 1; off < 256; off <<= 1) {
    int v = (tid >= off) ? sums[tid - off] : 0;
    __syncthreads();
    sums[tid] += v;
    __syncthreads();
  }
  int run = (tid == 0) ? 0 : sums[tid - 1];   // exclusive chunk prefix
  for (int i = 0; i < chunk; ++i) {
    prefix[base + i] = run;
    run += lens[base + i];
  }
}

// ---------------------------------------------------------------------------
// 2) per-sample ACE loss. One wave per sample, 4 samples per 256-thread block.
//    Lane mapping: tg = lane&15 covers t = 4*tg..4*tg+3 (float4 load),
//                  crow = lane>>4 covers c = 4*cc + crow.
//    A wave's 64 lanes read 1024 contiguous bytes per iteration.
// ---------------------------------------------------------------------------
__global__ __launch_bounds__(256) void ace_kernel(
    const float* __restrict__ x, const int* __restrict__ y,
    const int* __restrict__ lens, const int* __restrict__ prefix,
    float* __restrict__ loss_out) {
  const int wave = threadIdx.x >> 6;
  const int lane = threadIdx.x & 63;
  const int b = blockIdx.x * 4 + wave;
  const int tg = lane & 15;
  const int crow = lane >> 4;

  __shared__ int nk[4][NC];
  __shared__ int yk[4][NC];
  nk[wave][lane] = 0; nk[wave][lane + 64] = 0;
  yk[wave][lane] = 0; yk[wave][lane + 64] = 0;
  __syncthreads();

  const float4* xv = (const float4*)(x + (size_t)b * (NC * NT));

  float mv[4];
  int am[4];
#pragma unroll
  for (int j = 0; j < 4; ++j) { mv[j] = -FLT_MAX; am[j] = 0; }

#pragma unroll 8
  for (int cc = 0; cc < 32; ++cc) {
    const int c = cc * 4 + crow;
    float4 v = xv[c * (NT / 4) + tg];
    float vv[4] = {v.x, v.y, v.z, v.w};
#pragma unroll
    for (int j = 0; j < 4; ++j) {
      if (vv[j] > mv[j]) { mv[j] = vv[j]; am[j] = c; }   // strict > : first max
    }
  }

  // combine across the 4 lanes (crow dim) sharing one t-group; min index on tie
#pragma unroll
  for (int j = 0; j < 4; ++j) {
#pragma unroll
    for (int off = 16; off < 64; off <<= 1) {
      float om = __shfl_xor(mv[j], off, 64);
      int oa = __shfl_xor(am[j], off, 64);
      if (om > mv[j] || (om == mv[j] && oa < am[j])) { mv[j] = om; am[j] = oa; }
    }
  }

  // each lane records the argmax for time step t = 4*tg + crow
  // (avoid runtime register-array index: cndmask select chain)
  int my_am = am[0];
  if (crow == 1) my_am = am[1];
  if (crow == 2) my_am = am[2];
  if (crow == 3) my_am = am[3];
  atomicAdd(&nk[wave][my_am], 1);

  // target histogram for this sample
  const int len = lens[b];
  const int start = prefix[b];
  for (int i = lane; i < len; i += 64) atomicAdd(&yk[wave][y[start + i]], 1);
  __syncthreads();

  // loss: each lane handles classes lane and lane+64
  const int yk0 = yk[wave][lane], yk1 = yk[wave][lane + 64];
  const int nk0 = yk0 ? nk[wave][lane] : 0;
  const int nk1 = yk1 ? nk[wave][lane + 64] : 0;
  int ns = nk0 + nk1;
  int ys = yk0 + yk1;
#pragma unroll
  for (int off = 1; off < 64; off <<= 1) {
    ns += __shfl_xor(ns, off, 64);
    ys += __shfl_xor(ys, off, 64);
  }
  const float inv_ns = (ns > 0) ? (1.0f / (float)ns) : 0.0f;
  const float inv_ys = (ys > 0) ? (1.0f / (float)ys) : 0.0f;
  float acc = 0.0f;
  if (yk0) {
    float np = (ns == 0) ? ACE_EPS : fmaxf((float)nk0 * inv_ns, ACE_EPS);
    acc -= np * logf((float)yk0 * inv_ys);
  }
  if (yk1) {
    float np = (ns == 0) ? ACE_EPS : fmaxf((float)nk1 * inv_ns, ACE_EPS);
    acc -= np * logf((float)yk1 * inv_ys);
  }
#pragma unroll
  for (int off = 1; off < 64; off <<= 1) acc += __shfl_xor(acc, off, 64);
  if (lane == 0) loss_out[b] = acc;
}

// ---------------------------------------------------------------------------
// 3) deterministic mean over B per-sample losses — single 1024-thread block
// ---------------------------------------------------------------------------
__global__ void reduce_kernel(const float* __restrict__ loss,
                              float* __restrict__ out, int n) {
  __shared__ float s[1024];
  float a = 0.0f;
  for (int i = threadIdx.x; i < n; i += 1024) a += loss[i];
  s[threadIdx.x] = a;
  __syncthreads();
  for (int off = 512; off > 0; off >>= 1) {
    if ((int)threadIdx.x < off) s[threadIdx.x] += s[threadIdx.x + off];
    __syncthreads();
  }
  if (threadIdx.x == 0) out[0] = s[0] / (float)n;
}

extern "C" void kernel_launch(void* const* d_in, const int* in_sizes, int n_in,
                              void* d_out, int out_size, void* d_ws, size_t ws_size,
                              hipStream_t stream) {
  const float* x = (const float*)d_in[0];          // [B, C, T] f32
  const int* y = (const int*)d_in[1];              // [B*L] i32
  const int* lens = (const int*)d_in[2];           // [B] i32
  float* out = (float*)d_out;                      // scalar f32

  int* prefix = (int*)d_ws;                                  // B ints
  float* loss = (float*)((char*)d_ws + NB * sizeof(int));    // B floats

  prefix_kernel<<<1, 256, 0, stream>>>(lens, prefix, NB);
  ace_kernel<<<NB / 4, 256, 0, stream>>>(x, y, lens, prefix, loss);
  reduce_kernel<<<1, 1024, 0, stream>>>(loss, out, NB);
}